// Round 1
// baseline (490.558 us; speedup 1.0000x reference)
//
#include <hip/hip_runtime.h>
#include <hip/hip_bf16.h>

#define IN_F 4096
#define OUT_F 4096
#define M_ROWS 8192          // 4 * 2048
#define GROUP 128

#define KT_TILES (IN_F / 32)   // 128 k-tiles (32-k each) per row of tiled layout

// Tiled workspace layout ("fragment order"):
//   element [row][k] -> block ((row>>4)*KT_TILES + (k>>5)) of 512 shorts;
//   inner offset = (((k>>3)&3)*16 + (row&15))*8 + (k&7)
// so that global_load_lds (lds = base + lane*16) with per-lane gptr
// = tile_base + lane*16 stages a 1024 B CONTIGUOUS block that lands in LDS
// already in MFMA A/B fragment order (lane l = A[row=l&15][k=(l>>4)*8+j]).

typedef __attribute__((ext_vector_type(8))) short short8;
typedef __attribute__((ext_vector_type(4))) float floatx4;

__device__ __forceinline__ unsigned short f2bf(float f) {
    unsigned int u = __builtin_bit_cast(unsigned int, f);
    u += 0x7fffu + ((u >> 16) & 1u);   // RNE
    return (unsigned short)(u >> 16);
}

__device__ __forceinline__ void load_lds16(const unsigned short* g, unsigned short* l) {
    __builtin_amdgcn_global_load_lds(
        (const __attribute__((address_space(1))) void*)g,
        (__attribute__((address_space(3))) void*)l,
        16, 0, 0);
}

// ---------------------------------------------------------------------------
// Kernel 1: x fp32 -> xb_t bf16 tiled. Block: 16 rows x 256 k.
// Grid: (IN_F/256, M_ROWS/16) = (16, 512).
// ---------------------------------------------------------------------------
__global__ __launch_bounds__(256) void convert_x_kernel(const float* __restrict__ x,
                                                        unsigned short* __restrict__ xb) {
    __shared__ unsigned short tile[16 * 256];   // 8 KB, output (tiled) order

    const int t  = threadIdx.x;
    const int m0 = blockIdx.y * 16;
    const int k0 = blockIdx.x * 256;

    // phase 1: coalesced read (16 rows x 256 B segments), convert, LDS in tiled order
    {
        const int r = t & 15;
        const int c = t >> 4;                  // 0..15, 16 floats each
        const float4* src = (const float4*)(x + (size_t)(m0 + r) * IN_F + k0 + c * 16);
        float4 f[4];
#pragma unroll
        for (int i = 0; i < 4; ++i) f[i] = src[i];
        const float* fs = (const float*)f;
#pragma unroll
        for (int h = 0; h < 2; ++h) {          // two 8-element k-groups
            const int kl = c * 16 + h * 8;
            const int kt_l = kl >> 5;
            const int q    = (kl >> 3) & 3;
            union { unsigned short us[8]; uint4 v; } o;
#pragma unroll
            for (int j = 0; j < 8; ++j) o.us[j] = f2bf(fs[h * 8 + j]);
            *(uint4*)&tile[kt_l * 512 + (q * 16 + (t & 15)) * 8] = o.v;
        }
    }

    __syncthreads();

    // phase 2: linear copy LDS -> global (block's output is 8 KB contiguous)
    {
        unsigned short* dst = xb + ((size_t)blockIdx.y * KT_TILES + blockIdx.x * 8) * 512;
        *(uint4*)&dst[t * 8]        = *(const uint4*)&tile[t * 8];
        *(uint4*)&dst[2048 + t * 8] = *(const uint4*)&tile[2048 + t * 8];
    }
}

// ---------------------------------------------------------------------------
// Kernel 2: dequant -> wt_t bf16 tiled. Block: 64 n x 32 kp (=256 k).
// Grid: (512/32, 4096/64) = (16, 64).
// ---------------------------------------------------------------------------
#define DQ_KP 32
#define DQ_N  64

__global__ __launch_bounds__(256) void dequant_kernel(const int* __restrict__ qw,
                                                      const int* __restrict__ qz,
                                                      const float* __restrict__ sc,
                                                      unsigned short* __restrict__ wt) {
    __shared__ unsigned short tile[4 * 8 * 512];   // 32 KB: [tn_l][kt_l][512] tiled order

    const int t   = threadIdx.x;
    const int kp0 = blockIdx.x * DQ_KP;
    const int n0  = blockIdx.y * DQ_N;

    // phase 1: coalesced qweight read + dequant -> LDS in tiled order
    {
        const int kp_l = t >> 3;            // 0..31
        const int nq   = t & 7;             // 8-n chunk
        const int kp   = kp0 + kp_l;
        const int g    = kp >> 4;
        const int nb   = n0 + nq * 8;

        const uint4 q0 = *(const uint4*)&qw[(size_t)kp * OUT_F + nb];
        const uint4 q1 = *(const uint4*)&qw[(size_t)kp * OUT_F + nb + 4];
        const unsigned zq = (unsigned)qz[g * (OUT_F / 8) + (nb >> 3)];
        const float4 s0 = *(const float4*)&sc[(size_t)g * OUT_F + nb];
        const float4 s1 = *(const float4*)&sc[(size_t)g * OUT_F + nb + 4];

        unsigned qv[8] = {q0.x, q0.y, q0.z, q0.w, q1.x, q1.y, q1.z, q1.w};
        float    sv[8] = {s0.x, s0.y, s0.z, s0.w, s1.x, s1.y, s1.z, s1.w};

        const int kt_l  = kp_l >> 2;        // 0..7
        const int q_out = kp_l & 3;
        const int tn_l  = nq >> 1;

#pragma unroll
        for (int c = 0; c < 8; ++c) {
            const unsigned q = qv[c];
            const float zero = (float)(((zq >> (4 * c)) & 15u) + 1u);
            const float s = sv[c];
            const int r = (nq * 8 + c) & 15;
            union { unsigned short us[8]; uint4 v; } o;
#pragma unroll
            for (int j = 0; j < 8; ++j) {
                const float w = (float)((q >> (4 * j)) & 15u);
                o.us[j] = f2bf(s * (w - zero));
            }
            *(uint4*)&tile[(tn_l * 8 + kt_l) * 512 + (q_out * 16 + r) * 8] = o.v;
        }
    }

    __syncthreads();

    // phase 2: linear copy per n-tile (each tn_l = 8 KB contiguous in global)
    {
        const int tn0 = blockIdx.y * 4;
        const int kt0 = blockIdx.x * 8;
#pragma unroll
        for (int tn_l = 0; tn_l < 4; ++tn_l) {
            unsigned short* dst = wt + ((size_t)(tn0 + tn_l) * KT_TILES + kt0) * 512;
            const unsigned short* srcl = &tile[tn_l * 4096];
            *(uint4*)&dst[t * 8]        = *(const uint4*)&srcl[t * 8];
            *(uint4*)&dst[2048 + t * 8] = *(const uint4*)&srcl[2048 + t * 8];
        }
    }
}

// ---------------------------------------------------------------------------
// Kernel 3: bf16 MFMA GEMM, 256x256 tile, BK=32, 8 waves (2Mx4N), 512 thr.
// Phase-split schedule (T3+T4+T5): per K-step two {ds_read | prefetch-issue |
// barrier | lgkmcnt(0) | setprio(1) 16xMFMA setprio(0) | barrier} phases.
// Triple-buffered LDS (3 x 32 KB), prefetch 2 K-steps ahead, ONE counted
// s_waitcnt vmcnt(4) per K-step (never 0 until the tail) so staging loads
// get ~2 MFMA phases of latency slack instead of a full drain per K-step.
// Tiled inputs keep ds_read_b128 conflict-free (measured 0 conflicts).
// ---------------------------------------------------------------------------
__global__ __launch_bounds__(512, 2) void gemm_kernel(const unsigned short* __restrict__ xb,
                                                      const unsigned short* __restrict__ wt,
                                                      const float* __restrict__ bias,
                                                      float* __restrict__ out) {
    __shared__ unsigned short As[3 * 16 * 512];   // 48 KB: [buf][mt 0..15][512]
    __shared__ unsigned short Bs[3 * 16 * 512];   // 48 KB: [buf][nt 0..15][512]

    const int tid  = threadIdx.x;
    const int wid  = tid >> 6;          // 0..7
    const int lane = tid & 63;

    // XCD-aware bijective swizzle: 512 blocks, 8 XCDs, 64 consecutive logical
    // tiles per XCD = 4 full A-row-panels swept column-first (A panel 2 MiB
    // stays hot in the 4 MiB per-XCD L2).
    const int bid = blockIdx.x;
    const int swz = (bid & 7) * 64 + (bid >> 3);
    const int bx  = swz & 15;           // n-block 0..15
    const int by  = swz >> 4;           // m-block 0..31

    const int wm = wid & 1;             // wave row (2)
    const int wn = wid >> 1;            // wave col (4)

    const int TM0 = by * 16;            // first m-tile (16 rows each)
    const int TN0 = bx * 16;            // first n-tile

    floatx4 acc[8][4] = {};

    // staging: per K-step s, A-unit = 16 blocks of 1024 B (mt = r*8+wid, r=0,1),
    // B-unit likewise. 2 global_load_lds per thread per unit.
    const unsigned short* gA0 = xb + ((size_t)(TM0 + wid)     * KT_TILES) * 512 + lane * 8;
    const unsigned short* gA1 = xb + ((size_t)(TM0 + 8 + wid) * KT_TILES) * 512 + lane * 8;
    const unsigned short* gB0 = wt + ((size_t)(TN0 + wid)     * KT_TILES) * 512 + lane * 8;
    const unsigned short* gB1 = wt + ((size_t)(TN0 + 8 + wid) * KT_TILES) * 512 + lane * 8;

    unsigned short* lA0 = &As[wid * 512];
    unsigned short* lA1 = &As[(8 + wid) * 512];
    unsigned short* lB0 = &Bs[wid * 512];
    unsigned short* lB1 = &Bs[(8 + wid) * 512];

    const unsigned short* aBase = &As[(wm * 8) * 512 + lane * 8];
    const unsigned short* bBase = &Bs[(wn * 4) * 512 + lane * 8];

#define STAGE_A(buf, s) do { \
        load_lds16(gA0 + (size_t)(s) * 512, lA0 + (buf) * 8192); \
        load_lds16(gA1 + (size_t)(s) * 512, lA1 + (buf) * 8192); } while (0)
#define STAGE_B(buf, s) do { \
        load_lds16(gB0 + (size_t)(s) * 512, lB0 + (buf) * 8192); \
        load_lds16(gB1 + (size_t)(s) * 512, lB1 + (buf) * 8192); } while (0)

    // prologue: stage K-steps 0 and 1; require buf0 landed (allow buf1 in flight)
    STAGE_A(0, 0); STAGE_B(0, 0);
    STAGE_A(1, 1); STAGE_B(1, 1);
    asm volatile("s_waitcnt vmcnt(4)" ::: "memory");
    asm volatile("s_barrier" ::: "memory");

    int cur = 0, pre = 2;               // buf of K-step t, buf of K-step t+2
#pragma unroll 1
    for (int t = 0; t < 128; ++t) {
        const unsigned short* ab = aBase + cur * 8192;
        const unsigned short* bb = bBase + cur * 8192;

        short8 a[4], b[4];

        // ---- phase 1: read B-frags + A-quad0, issue A(t+2) prefetch ----
#pragma unroll
        for (int j = 0; j < 4; ++j) b[j] = *(const short8*)(bb + j * 512);
#pragma unroll
        for (int i = 0; i < 4; ++i) a[i] = *(const short8*)(ab + i * 512);
        if (t < 126) { STAGE_A(pre, t + 2); }
        asm volatile("s_barrier" ::: "memory");
        asm volatile("s_waitcnt lgkmcnt(0)" ::: "memory");
        __builtin_amdgcn_sched_barrier(0);
        __builtin_amdgcn_s_setprio(1);
#pragma unroll
        for (int i = 0; i < 4; ++i)
#pragma unroll
            for (int j = 0; j < 4; ++j)
                acc[i][j] = __builtin_amdgcn_mfma_f32_16x16x32_bf16(a[i], b[j], acc[i][j], 0, 0, 0);
        __builtin_amdgcn_s_setprio(0);
        __builtin_amdgcn_sched_barrier(0);
        asm volatile("s_barrier" ::: "memory");

        // ---- phase 2: read A-quad1, issue B(t+2) prefetch, counted vm gate ----
#pragma unroll
        for (int i = 0; i < 4; ++i) a[i] = *(const short8*)(ab + (4 + i) * 512);
        if (t < 126) {
            STAGE_B(pre, t + 2);
            // gate buffer t+1 complete; newest 4 loads (units for t+2) stay in flight
            asm volatile("s_waitcnt vmcnt(4)" ::: "memory");
        } else if (t == 126) {
            asm volatile("s_waitcnt vmcnt(0)" ::: "memory");   // tail drain (once)
        }
        asm volatile("s_barrier" ::: "memory");
        asm volatile("s_waitcnt lgkmcnt(0)" ::: "memory");
        __builtin_amdgcn_sched_barrier(0);
        __builtin_amdgcn_s_setprio(1);
#pragma unroll
        for (int i = 0; i < 4; ++i)
#pragma unroll
            for (int j = 0; j < 4; ++j)
                acc[4 + i][j] = __builtin_amdgcn_mfma_f32_16x16x32_bf16(a[i], b[j], acc[4 + i][j], 0, 0, 0);
        __builtin_amdgcn_s_setprio(0);
        __builtin_amdgcn_sched_barrier(0);
        asm volatile("s_barrier" ::: "memory");

        cur = (cur == 2) ? 0 : cur + 1;
        pre = (pre == 2) ? 0 : pre + 1;
    }
#undef STAGE_A
#undef STAGE_B

    // epilogue: C/D layout col = lane&15, row = (lane>>4)*4 + reg
    const int mrow = TM0 * 16 + wm * 128 + (lane >> 4) * 4;
    const int ncol = TN0 * 16 + wn * 64 + (lane & 15);
#pragma unroll
    for (int j = 0; j < 4; ++j) {
        const int n = ncol + j * 16;
        const float bv = bias[n];
#pragma unroll
        for (int i = 0; i < 8; ++i) {
            const int m = mrow + i * 16;
#pragma unroll
            for (int r = 0; r < 4; ++r)
                out[(size_t)(m + r) * OUT_F + n] = acc[i][j][r] + bv;
        }
    }
}

extern "C" void kernel_launch(void* const* d_in, const int* in_sizes, int n_in,
                              void* d_out, int out_size, void* d_ws, size_t ws_size,
                              hipStream_t stream) {
    const float* x    = (const float*)d_in[0];
    const int*   qw   = (const int*)d_in[1];
    const int*   qz   = (const int*)d_in[2];
    const float* sc   = (const float*)d_in[3];
    const float* bias = (const float*)d_in[4];
    float* out = (float*)d_out;

    unsigned short* xb = (unsigned short*)d_ws;                       // 64 MiB tiled
    unsigned short* wt = xb + (size_t)M_ROWS * IN_F;                  // +32 MiB tiled

    convert_x_kernel<<<dim3(IN_F / 256, M_ROWS / 16), 256, 0, stream>>>(x, xb);
    dequant_kernel<<<dim3(IN_F / 8 / DQ_KP, OUT_F / DQ_N), 256, 0, stream>>>(qw, qz, sc, wt);
    gemm_kernel<<<dim3((M_ROWS / 256) * (OUT_F / 256)), 512, 0, stream>>>(xb, wt, bias, out);
}